// Round 2
// baseline (228.740 us; speedup 1.0000x reference)
//
#include <hip/hip_runtime.h>
#include <math.h>

#define HEADS 8
#define DIM 16
#define NODES_PER_BLOCK 32   // 256 threads / 8 heads
// q,k,v layout: (N, D, H) -> flat idx = i*128 + d*8 + h
// out layout:   (N, D*H)  -> same flat indexing

__global__ __launch_bounds__(256) void spmha_kernel(
    const float* __restrict__ q, const float* __restrict__ k, const float* __restrict__ v,
    const int* __restrict__ row, const int* __restrict__ col,
    float* __restrict__ out, int N, int E) {
  __shared__ int rp[NODES_PER_BLOCK + 1];

  int node0 = blockIdx.x * NODES_PER_BLOCK;

  // 33 threads binary-search row_ptr for this block's node range. No global
  // scratch (d_ws may be smaller than N+1 ints — writing it corrupted the
  // harness's pristine buffers in round 1).
  if (threadIdx.x <= NODES_PER_BLOCK) {
    int target = node0 + threadIdx.x;   // may exceed N; search still safe
    int lo = 0, hi = E;
    while (lo < hi) {
      int mid = (lo + hi) >> 1;
      if (row[mid] < target) lo = mid + 1; else hi = mid;
    }
    rp[threadIdx.x] = lo;
  }
  __syncthreads();

  int t = blockIdx.x * blockDim.x + threadIdx.x;
  if (t >= N * HEADS) return;
  int il = threadIdx.x >> 3;          // local node index within block
  int i  = node0 + il;                // global node
  int h  = threadIdx.x & 7;           // head

  int s = rp[il];
  int e = rp[il + 1];

  // Query vector for (i, h): 16 floats at stride 8.
  const float* qb = q + (size_t)i * 128 + h;
  float qv[DIM];
#pragma unroll
  for (int d = 0; d < DIM; ++d) qv[d] = qb[d * 8];

  // Online softmax + output accumulator, all in registers.
  float m = -INFINITY;
  float den = 0.f;
  float o[DIM];
#pragma unroll
  for (int d = 0; d < DIM; ++d) o[d] = 0.f;

  for (int eidx = s; eidx < e; ++eidx) {
    int c = col[eidx];  // broadcast across the 8 lanes of this node
    const float* kb = k + (size_t)c * 128 + h;
    const float* vb = v + (size_t)c * 128 + h;

    float l = 0.f;
#pragma unroll
    for (int d = 0; d < DIM; ++d) l = fmaf(qv[d], kb[d * 8], l);

    float mn = fmaxf(m, l);
    float scale = __expf(m - mn);   // m=-inf first iter -> 0
    float p = __expf(l - mn);
    den = fmaf(den, scale, p);
#pragma unroll
    for (int d = 0; d < DIM; ++d) o[d] = fmaf(o[d], scale, p * vb[d * 8]);
    m = mn;
  }

  float inv = (e > s) ? 1.f / den : 0.f;  // degree-0 node -> zeros (matches ref)
  float* ob = out + (size_t)i * 128 + h;
#pragma unroll
  for (int d = 0; d < DIM; ++d) ob[d * 8] = o[d] * inv;
}

extern "C" void kernel_launch(void* const* d_in, const int* in_sizes, int n_in,
                              void* d_out, int out_size, void* d_ws, size_t ws_size,
                              hipStream_t stream) {
  const float* q   = (const float*)d_in[0];
  const float* k   = (const float*)d_in[1];
  const float* v   = (const float*)d_in[2];
  const int*   row = (const int*)d_in[3];
  const int*   col = (const int*)d_in[4];
  float* out = (float*)d_out;

  int N = in_sizes[0] / (DIM * HEADS);
  int E = in_sizes[3];

  int total = N * HEADS;
  int grid = (total + 255) / 256;
  spmha_kernel<<<grid, 256, 0, stream>>>(q, k, v, row, col, out, N, E);
}